// Round 5
// baseline (64257.965 us; speedup 1.0000x reference)
//
#include <hip/hip_runtime.h>
#include <hip/hip_fp16.h>

// LSTM (2-layer bidirectional, B=64 T=1024 I=H=256) for MI355X.
// R5 (= R4 resubmit + LDS pad fix + xf kept f16): NO cross-WG communication.
// Per direction, the FULL W_hh (512KB f16, B-fragment layout) is held by ONE
// workgroup: 384KB in VGPR/AGPR (unified file) + 128KB in LDS. Batch is split
// 4x (independent chains): 8 WGs of 256 threads (dir x batch-chunk of 16).
// Recurrence entirely intra-WG: h in double-buffered LDS, ONE barrier/step.
// d_out = o2 [B,T,512] fp32 ++ h_n [4,B,H] ++ c_n [4,B,H].

#define BQ 64
#define TT 1024
#define II 256
#define M0 (BQ * TT)  // 65536
#define HPAD 264      // h row stride in halfs: 528B, mod 128B = 16B -> 2-way (free)

typedef _Float16 half8 __attribute__((ext_vector_type(8)));
typedef float floatx4 __attribute__((ext_vector_type(4)));

__device__ __forceinline__ float fsig(float x) {
  float e = __builtin_amdgcn_exp2f(-1.44269504089f * x);
  return __builtin_amdgcn_rcpf(1.0f + e);
}
__device__ __forceinline__ float ftanh(float x) {
  float ax = __builtin_fabsf(x);
  float e = __builtin_amdgcn_exp2f(-2.88539008178f * ax);
  float r = (1.0f - e) * __builtin_amdgcn_rcpf(1.0f + e);
  return __builtin_copysignf(r, x);
}
__device__ __forceinline__ half8 cvt8(float4 a, float4 b) {
  half8 h;
  h[0] = (_Float16)a.x; h[1] = (_Float16)a.y; h[2] = (_Float16)a.z; h[3] = (_Float16)a.w;
  h[4] = (_Float16)b.x; h[5] = (_Float16)b.y; h[6] = (_Float16)b.z; h[7] = (_Float16)b.w;
  return h;
}

// x [B,T,I] fp32 -> xT [(t*B+b), I] f16
__global__ __launch_bounds__(256) void pack_xT(const float* __restrict__ x,
                                               _Float16* __restrict__ xT) {
  int gid = blockIdx.x * 256 + threadIdx.x;  // one thread per 8 elems
  int chunk = gid & 31;
  int row = gid >> 5;  // row = t*64 + b
  int t = row >> 6, b = row & 63;
  const float* src = x + ((size_t)b * TT + t) * II + chunk * 8;
  float4 v0 = *(const float4*)src;
  float4 v1 = *(const float4*)(src + 4);
  *(half8*)(xT + (size_t)row * II + chunk * 8) = cvt8(v0, v1);
}

// W fp32 [D][1024][K] -> f16 B-fragment layout [d][tile][ks][lane][8]
// fragment: n = tile*16 + (lane&15), k = ks*32 + (lane>>4)*8 + j
__global__ __launch_bounds__(256) void pack_B(const float* __restrict__ W,
                                              _Float16* __restrict__ dst, int K,
                                              int total) {
  int gid = blockIdx.x * 256 + threadIdx.x;
  if (gid >= total) return;
  int per = 64 * (K / 32) * 64;  // threads per dir
  int d = gid / per;
  int i = gid - d * per;
  int lane = i & 63;
  int i2 = i >> 6;  // tile*(K/32) + ks
  int n = (i2 / (K / 32)) * 16 + (lane & 15);
  int k = (i2 % (K / 32)) * 32 + (lane >> 4) * 8;
  const float* s = W + ((size_t)d * 1024 + n) * K + k;
  float4 v0 = *(const float4*)s;
  float4 v1 = *(const float4*)(s + 4);
  *(half8*)(dst + (size_t)gid * 8) = cvt8(v0, v1);
}

__global__ __launch_bounds__(256) void add_bias(const float* __restrict__ a,
                                                const float* __restrict__ b,
                                                float* __restrict__ o, int n) {
  int i = blockIdx.x * 256 + threadIdx.x;
  if (i < n) o[i] = a[i] + b[i];
}

// out[d][m][n] = sum_k A[m][k]*W[d][n][k] + bias[d][n], f16 store. M=65536, N=1024.
// 128x128 tile, 4 waves (2x2), 4x4 16x16x32 f16 MFMA per wave. (R2-proven form.)
template <int K>
__global__ __launch_bounds__(256) void gemm_xg(const _Float16* __restrict__ A,
                                               const _Float16* __restrict__ Bp,
                                               const float* __restrict__ bias,
                                               _Float16* __restrict__ out) {
  const int d = blockIdx.z;
  const int n0 = blockIdx.x * 128;
  const int m0 = blockIdx.y * 128;
  const int tid = threadIdx.x;
  const int lane = tid & 63, wave = tid >> 6;
  const int wr = wave >> 1, wc = wave & 1;
  const int cl = lane & 15, lh = lane >> 4;
  __shared__ _Float16 As[128][48];  // pad 32->48
  const _Float16* Bb = Bp + (size_t)d * (1024 * K);
  floatx4 acc[4][4];
#pragma unroll
  for (int i = 0; i < 4; i++)
#pragma unroll
    for (int j = 0; j < 4; j++) acc[i][j] = (floatx4){0.f, 0.f, 0.f, 0.f};

  for (int ks = 0; ks < K / 32; ++ks) {
#pragma unroll
    for (int it = 0; it < 2; ++it) {  // stage A tile 128x32 f16
      int row = it * 64 + (tid >> 2);
      int col = (tid & 3) * 8;
      *(half8*)(&As[row][col]) =
          *(const half8*)(A + (size_t)(m0 + row) * K + ks * 32 + col);
    }
    __syncthreads();
    half8 a[4], b[4];
#pragma unroll
    for (int rt = 0; rt < 4; rt++)
      a[rt] = *(const half8*)(&As[wr * 64 + rt * 16 + cl][lh * 8]);
#pragma unroll
    for (int ct = 0; ct < 4; ct++) {
      int tile = (n0 >> 4) + wc * 4 + ct;
      b[ct] = *(const half8*)(Bb + ((size_t)(tile * (K / 32) + ks) * 64 + lane) * 8);
    }
#pragma unroll
    for (int rt = 0; rt < 4; rt++)
#pragma unroll
      for (int ct = 0; ct < 4; ct++)
        acc[rt][ct] = __builtin_amdgcn_mfma_f32_16x16x32_f16(a[rt], b[ct], acc[rt][ct], 0, 0, 0);
    __syncthreads();
  }
#pragma unroll
  for (int ct = 0; ct < 4; ct++) {
    int n = n0 + wc * 64 + ct * 16 + cl;
    float bv = bias[d * 1024 + n];
#pragma unroll
    for (int rt = 0; rt < 4; rt++) {
      int mb = m0 + wr * 64 + rt * 16 + lh * 4;
#pragma unroll
      for (int r = 0; r < 4; r++)
        out[(size_t)d * ((size_t)M0 * 1024) + (size_t)(mb + r) * 1024 + n] =
            (_Float16)(acc[rt][ct][r] + bv);
    }
  }
}

// Persistent intra-WG recurrence. 8 WGs: dir = wg>>2, batch chunk b0=(wg&3)*16.
// 256 threads = 4 waves (1/SIMD, reg budget ~512). Wave w owns hidden-tiles
// jt = w + 4*ji (ji=0..3): N-tiles T = g*16 + w + 4*ji for gates g. ji=0..2
// in registers (w[3][4][8] half8 = 384 VGPRs); ji=3 in LDS (128KB). h
// double-buffered in LDS. Step split in halves (ji 0,1 | 2,3) to cap acc/xf.
template <int LAYER>
__global__ __launch_bounds__(256, 1) void lstm_rec(
    const _Float16* __restrict__ xg, const _Float16* __restrict__ Whp,
    _Float16* __restrict__ o1, float* __restrict__ out) {
  const int wg = blockIdx.x;
  const int dir = wg >> 2;
  const int b0 = (wg & 3) << 4;
  const int tid = threadIdx.x;
  const int lane = tid & 63, wave = tid >> 6;
  const int cl = lane & 15, lh = lane >> 4;
  const size_t o2elems = (size_t)BQ * TT * 512;

  __shared__ half8 lw8[4 * 4 * 8 * 64];   // 128KB: ji=3 tiles, [wave][g][ks][lane]
  __shared__ _Float16 hl[2][16][HPAD];    // ~16.5KB: h double buffer

  const _Float16* Wb = Whp + (size_t)dir * (1024 * 256);
  // Register-resident weight fragments: ji=0..2.
  half8 w[3][4][8];
#pragma unroll
  for (int ji = 0; ji < 3; ji++)
#pragma unroll
    for (int g = 0; g < 4; g++)
#pragma unroll
      for (int ks = 0; ks < 8; ks++)
        w[ji][g][ks] =
            *(const half8*)(Wb + ((size_t)((g * 16 + wave + 4 * ji) * 8 + ks) * 64 + lane) * 8);
  // LDS-resident weight fragments: ji=3.
#pragma unroll
  for (int g = 0; g < 4; g++)
#pragma unroll
    for (int ks = 0; ks < 8; ks++)
      lw8[((wave * 4 + g) * 8 + ks) * 64 + lane] =
          *(const half8*)(Wb + ((size_t)((g * 16 + wave + 12) * 8 + ks) * 64 + lane) * 8);
  // zero h buffers
  for (int i = tid; i < 2 * 16 * HPAD; i += 256) (&hl[0][0][0])[i] = (_Float16)0.f;

  float c[4][4];
#pragma unroll
  for (int ji = 0; ji < 4; ji++)
#pragma unroll
    for (int r = 0; r < 4; r++) c[ji][r] = 0.f;
  __syncthreads();

  for (int t = 0; t < TT; ++t) {
    const int tt = dir ? (TT - 1 - t) : t;
    const int p = t & 1;
    const _Float16* xgrow = xg + ((size_t)dir * M0 + (size_t)tt * BQ + b0) * 1024;

#pragma unroll
    for (int hf = 0; hf < 2; hf++) {
      // xg gate pre-activations for this half (scattered 2B; kept f16 = packed
      // 2/VGPR to stay under the 512-reg cliff; converted at gate time)
      _Float16 xf[2][4][4];
#pragma unroll
      for (int jih = 0; jih < 2; jih++)
#pragma unroll
        for (int g = 0; g < 4; g++)
#pragma unroll
          for (int r = 0; r < 4; r++)
            xf[jih][g][r] = xgrow[(size_t)(lh * 4 + r) * 1024 + g * 256 +
                                  (wave + 4 * (2 * hf + jih)) * 16 + cl];
      floatx4 acc[2][4];
#pragma unroll
      for (int jih = 0; jih < 2; jih++)
#pragma unroll
        for (int g = 0; g < 4; g++) acc[jih][g] = (floatx4){0.f, 0.f, 0.f, 0.f};
#pragma unroll
      for (int ks = 0; ks < 8; ks++) {
        half8 a = *(const half8*)(&hl[p][cl][ks * 32 + lh * 8]);
#pragma unroll
        for (int jih = 0; jih < 2; jih++) {
#pragma unroll
          for (int g = 0; g < 4; g++) {
            half8 b;
            if (hf == 1 && jih == 1)
              b = lw8[((wave * 4 + g) * 8 + ks) * 64 + lane];
            else
              b = w[2 * hf + jih][g][ks];
            acc[jih][g] = __builtin_amdgcn_mfma_f32_16x16x32_f16(a, b, acc[jih][g], 0, 0, 0);
          }
        }
      }
      // gates: lane holds i,f,g,o of hidden j = (wave+4*ji)*16+cl, rows lh*4+r
#pragma unroll
      for (int jih = 0; jih < 2; jih++) {
        const int ji = 2 * hf + jih;
        const int j = (wave + 4 * ji) * 16 + cl;
#pragma unroll
        for (int r = 0; r < 4; r++) {
          const int row = lh * 4 + r;
          float gi = acc[jih][0][r] + (float)xf[jih][0][r];
          float gf = acc[jih][1][r] + (float)xf[jih][1][r];
          float gg = acc[jih][2][r] + (float)xf[jih][2][r];
          float go = acc[jih][3][r] + (float)xf[jih][3][r];
          float cc = fsig(gf) * c[ji][r] + fsig(gi) * ftanh(gg);
          c[ji][r] = cc;
          float h = fsig(go) * ftanh(cc);
          hl[p ^ 1][row][j] = (_Float16)h;
          if (LAYER == 0) {
            o1[((size_t)tt * BQ + b0 + row) * 512 + dir * 256 + j] = (_Float16)h;
          } else {
            out[((size_t)(b0 + row) * TT + tt) * 512 + dir * 256 + j] = h;
          }
          if (t == TT - 1) {
            const int hrow = LAYER * 2 + dir;
            out[o2elems + ((size_t)hrow * BQ + b0 + row) * 256 + j] = h;
            out[o2elems + (size_t)4 * BQ * 256 + ((size_t)hrow * BQ + b0 + row) * 256 + j] = cc;
          }
        }
      }
    }
    __syncthreads();  // new h (buffer p^1) visible; all reads of buffer p done
  }
}

extern "C" void kernel_launch(void* const* d_in, const int* in_sizes, int n_in,
                              void* d_out, int out_size, void* d_ws, size_t ws_size,
                              hipStream_t stream) {
  (void)in_sizes; (void)n_in; (void)out_size; (void)ws_size;
  const float* x = (const float*)d_in[0];
  // d_in[1] = hidden_state, ignored by the module
  const float* wih0 = (const float*)d_in[2];
  const float* whh0 = (const float*)d_in[3];
  const float* bih0 = (const float*)d_in[4];
  const float* bhh0 = (const float*)d_in[5];
  const float* wih1 = (const float*)d_in[6];
  const float* whh1 = (const float*)d_in[7];
  const float* bih1 = (const float*)d_in[8];
  const float* bhh1 = (const float*)d_in[9];
  float* out = (float*)d_out;

  char* p = (char*)d_ws;  // ~359 MB total
  _Float16* xT = (_Float16*)p;    p += (size_t)M0 * II * 2;        // 32 MB
  _Float16* o1 = (_Float16*)p;    p += (size_t)M0 * 512 * 2;       // 64 MB
  _Float16* xgb = (_Float16*)p;   p += (size_t)2 * M0 * 1024 * 2;  // 256 MB
  _Float16* pwih0 = (_Float16*)p; p += (size_t)2 * 1024 * 256 * 2;
  _Float16* pwhh0 = (_Float16*)p; p += (size_t)2 * 1024 * 256 * 2;
  _Float16* pwih1 = (_Float16*)p; p += (size_t)2 * 1024 * 512 * 2;
  _Float16* pwhh1 = (_Float16*)p; p += (size_t)2 * 1024 * 256 * 2;
  float* bias0 = (float*)p;       p += 2 * 1024 * 4;
  float* bias1 = (float*)p;       p += 2 * 1024 * 4;

  hipLaunchKernelGGL(pack_xT, dim3(8192), dim3(256), 0, stream, x, xT);
  hipLaunchKernelGGL(pack_B, dim3(256), dim3(256), 0, stream, wih0, pwih0, 256, 2 * 1024 * 256 / 8);
  hipLaunchKernelGGL(pack_B, dim3(256), dim3(256), 0, stream, whh0, pwhh0, 256, 2 * 1024 * 256 / 8);
  hipLaunchKernelGGL(pack_B, dim3(512), dim3(256), 0, stream, wih1, pwih1, 512, 2 * 1024 * 512 / 8);
  hipLaunchKernelGGL(pack_B, dim3(256), dim3(256), 0, stream, whh1, pwhh1, 256, 2 * 1024 * 256 / 8);
  hipLaunchKernelGGL(add_bias, dim3(8), dim3(256), 0, stream, bih0, bhh0, bias0, 2048);
  hipLaunchKernelGGL(add_bias, dim3(8), dim3(256), 0, stream, bih1, bhh1, bias1, 2048);

  hipLaunchKernelGGL((gemm_xg<256>), dim3(8, 512, 2), dim3(256), 0, stream, xT, pwih0, bias0, xgb);
  hipLaunchKernelGGL((lstm_rec<0>), dim3(8), dim3(256), 0, stream, xgb, pwhh0, o1, out);
  hipLaunchKernelGGL((gemm_xg<512>), dim3(8, 512, 2), dim3(256), 0, stream, o1, pwih1, bias1, xgb);
  hipLaunchKernelGGL((lstm_rec<1>), dim3(8), dim3(256), 0, stream, xgb, pwhh1, (_Float16*)nullptr, out);
}